// Round 2
// baseline (14567.264 us; speedup 1.0000x reference)
//
#include <hip/hip_runtime.h>
#include <hip/hip_cooperative_groups.h>
#include <math.h>

namespace cg = cooperative_groups;

#define B_ 512
#define N_ 20
#define H_ 450
#define L_ 56
#define V_ 780
#define T_ 38
#define NNODES (B_*N_)        // 10240
#define NEDGES (B_*2*(N_-1))  // 19456
#define NPROWS ((T_+1)*B_)    // 19968
#define K2H 900               // 2*H
#define MAXP 8
#define MAXD 8
#define SCAN_GRID 240         // 16 row-tiles x 15 col-tiles

__device__ __forceinline__ float sigmoidf_(float v){ return 1.0f/(1.0f+expf(-v)); }

// x[i][:] = emb[wid[i]][:]
__global__ void k_gather_x(const float* __restrict__ emb, const int* __restrict__ wid,
                           float* __restrict__ x){
  int i = blockIdx.x; int w = wid[i];
  for (int j = threadIdx.x; j < H_; j += blockDim.x)
    x[(size_t)i*H_+j] = emb[(size_t)w*H_+j];
}

struct ScanParams {
  const float *x, *Wz, *bz, *Wh, *bh, *Wr, *Ur, *br;
  const int *edge_src, *edge_dst, *edge_pred, *node_in, *step_eid, *step_v;
  float *m, *rm, *h_steps;
  int P, Dn;
};

// One persistent cooperative kernel for all 38 DFS steps.
// Phase A: m_new = (1-z)*s + z*tanh([sx|arm]@Wh+bh), z=sigmoid([sx|s]@Wz+bz); scatter to m[eid].
// grid.sync (m visible)
// Phase B: r = sigmoid([dx|m_new]@[Wr;Ur]+br); rm[eid]=r*m_new; h_steps[t]=sum m[node_in[v]].
// grid.sync (rm visible for next step's pred sums)
__global__ __launch_bounds__(256) void k_scan(ScanParams p){
  cg::grid_group grid = cg::this_grid();
  const int bid = blockIdx.x;
  const int rt = bid / 15, ct = bid % 15;
  const int r0 = rt * 32, c0 = ct * 32;
  const int tid = threadIdx.x;
  const int tx = tid & 15, ty = tid >> 4;
  const int lr = ty * 2, lc = tx * 2;
  const int P = p.P, Dn = p.Dn;

  __shared__ float As1[32][36], As2[32][36];   // [row][k], padded to 144B stride
  __shared__ float Wt1[32][36], Wt2[32][36];   // [col][k] transposed weight tiles
  __shared__ int s_eoff[32], s_soff[32], s_doff[32];
  __shared__ int s_poff[32][MAXP];
  __shared__ int s_noff[32][MAXD];

  for (int t = 0; t < T_; ++t){
    // ---- per-step row metadata ----
    if (tid < 32){
      int b = r0 + tid;
      int e = p.step_eid[t*B_ + b];
      s_eoff[tid] = e * H_;
      s_soff[tid] = p.edge_src[e] * H_;
      s_doff[tid] = p.edge_dst[e] * H_;
      int v = p.step_v[t*B_ + b];
      for (int q = 0; q < P; ++q) s_poff[tid][q] = p.edge_pred[e*P + q] * H_;
      for (int d = 0; d < Dn; ++d) s_noff[tid][d] = p.node_in[v*Dn + d] * H_;
    }
    __syncthreads();

    // ================= Phase A =================
    float accZ[2][2] = {{0.f,0.f},{0.f,0.f}};
    float accH[2][2] = {{0.f,0.f},{0.f,0.f}};
    for (int kt = 0; kt < K2H; kt += 32){
      // A tiles: [sx|s] and [sx|arm]
      for (int l = tid; l < 1024; l += 256){
        int c = l & 31, r = l >> 5;
        int gk = kt + c;
        float a1 = 0.f, a2 = 0.f;
        if (gk < H_){
          float v = p.x[s_soff[r] + gk];
          a1 = v; a2 = v;
        } else if (gk < K2H){
          int j = gk - H_;
          float s = 0.f, ar = 0.f;
          for (int q = 0; q < P; ++q){ int o = s_poff[r][q]; s += p.m[o + j]; ar += p.rm[o + j]; }
          a1 = s; a2 = ar;
        }
        As1[r][c] = a1; As2[r][c] = a2;
      }
      // W tiles transposed: Wt[col][k]
      for (int l = tid; l < 1024; l += 256){
        int c = l & 31, r = l >> 5;       // r = k index, c = col
        int gk = kt + r, gc = c0 + c;
        float w1 = 0.f, w2 = 0.f;
        if (gk < K2H && gc < H_){ w1 = p.Wz[(size_t)gk*H_ + gc]; w2 = p.Wh[(size_t)gk*H_ + gc]; }
        Wt1[c][r] = w1; Wt2[c][r] = w2;
      }
      __syncthreads();
      #pragma unroll
      for (int kk = 0; kk < 32; kk += 4){
        float a1a[4], a1b[4], a2a[4], a2b[4], w1a[4], w1b[4], w2a[4], w2b[4];
        *(float4*)a1a = *(const float4*)&As1[lr  ][kk];
        *(float4*)a1b = *(const float4*)&As1[lr+1][kk];
        *(float4*)a2a = *(const float4*)&As2[lr  ][kk];
        *(float4*)a2b = *(const float4*)&As2[lr+1][kk];
        *(float4*)w1a = *(const float4*)&Wt1[lc  ][kk];
        *(float4*)w1b = *(const float4*)&Wt1[lc+1][kk];
        *(float4*)w2a = *(const float4*)&Wt2[lc  ][kk];
        *(float4*)w2b = *(const float4*)&Wt2[lc+1][kk];
        #pragma unroll
        for (int u = 0; u < 4; ++u){
          accZ[0][0] += a1a[u]*w1a[u]; accZ[0][1] += a1a[u]*w1b[u];
          accZ[1][0] += a1b[u]*w1a[u]; accZ[1][1] += a1b[u]*w1b[u];
          accH[0][0] += a2a[u]*w2a[u]; accH[0][1] += a2a[u]*w2b[u];
          accH[1][0] += a2b[u]*w2a[u]; accH[1][1] += a2b[u]*w2b[u];
        }
      }
      __syncthreads();
    }
    // epilogue A: m[eid] = (1-z)*s + z*tanh
    #pragma unroll
    for (int ii = 0; ii < 2; ++ii){
      int r = lr + ii;
      #pragma unroll
      for (int jj = 0; jj < 2; ++jj){
        int gc = c0 + lc + jj;
        if (gc < H_){
          float z  = sigmoidf_(accZ[ii][jj] + p.bz[gc]);
          float th = tanhf(accH[ii][jj] + p.bh[gc]);
          float s = 0.f;
          for (int q = 0; q < P; ++q) s += p.m[s_poff[r][q] + gc];
          p.m[s_eoff[r] + gc] = (1.f - z)*s + z*th;
        }
      }
    }
    __threadfence();
    grid.sync();

    // ================= Phase B =================
    float accR[2][2] = {{0.f,0.f},{0.f,0.f}};
    for (int kt = 0; kt < K2H; kt += 32){
      for (int l = tid; l < 1024; l += 256){
        int c = l & 31, r = l >> 5;
        int gk = kt + c;
        float a = 0.f;
        if (gk < H_)       a = p.x[s_doff[r] + gk];
        else if (gk < K2H) a = p.m[s_eoff[r] + (gk - H_)];
        As1[r][c] = a;
      }
      for (int l = tid; l < 1024; l += 256){
        int c = l & 31, r = l >> 5;
        int gk = kt + r, gc = c0 + c;
        float w = 0.f;
        if (gk < K2H && gc < H_)
          w = (gk < H_) ? p.Wr[(size_t)gk*H_ + gc] : p.Ur[(size_t)(gk - H_)*H_ + gc];
        Wt1[c][r] = w;
      }
      __syncthreads();
      #pragma unroll
      for (int kk = 0; kk < 32; kk += 4){
        float aa[4], ab[4], wa[4], wb[4];
        *(float4*)aa = *(const float4*)&As1[lr  ][kk];
        *(float4*)ab = *(const float4*)&As1[lr+1][kk];
        *(float4*)wa = *(const float4*)&Wt1[lc  ][kk];
        *(float4*)wb = *(const float4*)&Wt1[lc+1][kk];
        #pragma unroll
        for (int u = 0; u < 4; ++u){
          accR[0][0] += aa[u]*wa[u]; accR[0][1] += aa[u]*wb[u];
          accR[1][0] += ab[u]*wa[u]; accR[1][1] += ab[u]*wb[u];
        }
      }
      __syncthreads();
    }
    // epilogue B: rm[eid] = r*m_new; h_steps[t] = sum m[node_in[v]]
    #pragma unroll
    for (int ii = 0; ii < 2; ++ii){
      int r = lr + ii;
      int b = r0 + r;
      #pragma unroll
      for (int jj = 0; jj < 2; ++jj){
        int gc = c0 + lc + jj;
        if (gc < H_){
          float r_ = sigmoidf_(accR[ii][jj] + p.br[gc]);
          float mn = p.m[s_eoff[r] + gc];
          p.rm[s_eoff[r] + gc] = r_ * mn;
          float h = 0.f;
          for (int d = 0; d < Dn; ++d) h += p.m[s_noff[r][d] + gc];
          p.h_steps[((size_t)t*B_ + b)*H_ + gc] = h;
        }
      }
    }
    __threadfence();
    grid.sync();
  }
}

// Virtual-A gather for head GEMMs. mode 0: q rows; mode 1: p rows; mode 2: plain.
__device__ __forceinline__ float headA(int mode, int gi, int gk, int K,
    const float* __restrict__ Aplain, const float* __restrict__ x,
    const float* __restrict__ h_steps, const float* __restrict__ tree_vec,
    const int* __restrict__ q_rows, const int* __restrict__ root_ids,
    const int* __restrict__ step_v){
  if (mode == 2) return Aplain[(size_t)gi*K + gk];
  if (mode == 0){
    int row = q_rows[gi];
    int b = row & (B_-1);
    if (gk < H_) return (row < B_) ? 0.f : h_steps[(size_t)(row - B_)*H_ + gk];
    return tree_vec[b*L_ + (gk - H_)];
  }
  int b = gi & (B_-1);
  if (gk < H_){
    int xn = (gi < B_) ? root_ids[b] : step_v[gi - B_];
    return x[(size_t)xn*H_ + gk];
  }
  if (gk < 2*H_) return (gi < B_) ? 0.f : h_steps[(size_t)(gi - B_)*H_ + (gk - H_)];
  return tree_vec[b*L_ + (gk - 2*H_)];
}

// 64x64 tile, 256 threads, 4x4 per thread, BK=16.
__global__ __launch_bounds__(256) void k_mm64(
    int rows, int cols, int K, int mode, int act,
    const float* __restrict__ Aplain, const float* __restrict__ W,
    const float* __restrict__ bias, float* __restrict__ C,
    const float* __restrict__ x, const float* __restrict__ h_steps,
    const float* __restrict__ tree_vec, const int* __restrict__ q_rows,
    const int* __restrict__ root_ids, const int* __restrict__ step_v){
  __shared__ float As[16][68];   // [k][row], 272B stride (16B aligned)
  __shared__ float Ws[16][68];   // [k][col]
  const int tid = threadIdx.x, tx = tid & 15, ty = tid >> 4;
  const int gr0 = blockIdx.y * 64, gc0 = blockIdx.x * 64;
  float acc[4][4] = {};
  for (int kt = 0; kt < K; kt += 16){
    for (int l = tid; l < 1024; l += 256){
      int row = l & 63, k = l >> 6;
      int gi = gr0 + row, gk = kt + k;
      float a = 0.f;
      if (gi < rows && gk < K)
        a = headA(mode, gi, gk, K, Aplain, x, h_steps, tree_vec, q_rows, root_ids, step_v);
      As[k][row] = a;
    }
    for (int l = tid; l < 1024; l += 256){
      int c = l & 63, k = l >> 6;
      int gk = kt + k, gc = gc0 + c;
      Ws[k][c] = (gk < K && gc < cols) ? W[(size_t)gk*cols + gc] : 0.f;
    }
    __syncthreads();
    #pragma unroll
    for (int kk = 0; kk < 16; ++kk){
      float av[4], wv[4];
      *(float4*)av = *(const float4*)&As[kk][ty*4];
      *(float4*)wv = *(const float4*)&Ws[kk][tx*4];
      #pragma unroll
      for (int i = 0; i < 4; ++i)
        #pragma unroll
        for (int j = 0; j < 4; ++j)
          acc[i][j] += av[i]*wv[j];
    }
    __syncthreads();
  }
  for (int i = 0; i < 4; ++i){
    int gi = gr0 + ty*4 + i;
    if (gi >= rows) continue;
    for (int j = 0; j < 4; ++j){
      int gc = gc0 + tx*4 + j;
      if (gc >= cols) continue;
      float v = acc[i][j] + bias[gc];
      if (act) v = fmaxf(v, 0.f);
      C[(size_t)gi*cols + gc] = v;
    }
  }
}

// Per-row: lse, argmax (first occurrence), target logit -> q_loss, q_acc
__global__ __launch_bounds__(256) void k_qreduce(const float* __restrict__ logits,
    const int* __restrict__ q_tgt, int nq, float* __restrict__ out){
  __shared__ float smax[256]; __shared__ int sidx[256]; __shared__ float ssum[256];
  int i = blockIdx.x;
  const float* lr = logits + (size_t)i*V_;
  float mx = -INFINITY; int mi = 0;
  for (int j = threadIdx.x; j < V_; j += 256){
    float v = lr[j];
    if (v > mx){ mx = v; mi = j; }
  }
  smax[threadIdx.x] = mx; sidx[threadIdx.x] = mi;
  __syncthreads();
  for (int s = 128; s > 0; s >>= 1){
    if (threadIdx.x < s){
      float v2 = smax[threadIdx.x+s]; int i2 = sidx[threadIdx.x+s];
      float v1 = smax[threadIdx.x];   int i1 = sidx[threadIdx.x];
      if (v2 > v1 || (v2 == v1 && i2 < i1)){ smax[threadIdx.x] = v2; sidx[threadIdx.x] = i2; }
    }
    __syncthreads();
  }
  float gmax = smax[0]; int gidx = sidx[0];
  float ps = 0.f;
  for (int j = threadIdx.x; j < V_; j += 256) ps += expf(lr[j]-gmax);
  ssum[threadIdx.x] = ps; __syncthreads();
  for (int s = 128; s > 0; s >>= 1){
    if (threadIdx.x < s) ssum[threadIdx.x] += ssum[threadIdx.x+s];
    __syncthreads();
  }
  if (threadIdx.x == 0){
    float lse = gmax + logf(ssum[0]);
    int tg = q_tgt[i];
    atomicAdd(out+0, (lse - lr[tg]) * (1.0f/B_));
    atomicAdd(out+2, (gidx == tg) ? (1.0f/(float)nq) : 0.f);
  }
}

// Per-row: p_logit = hidden.Us + bs -> BCE loss + acc
__global__ __launch_bounds__(256) void k_preduce(const float* __restrict__ hiddenp,
    const float* __restrict__ Us, const float* __restrict__ bs,
    const int* __restrict__ p_tgt, float* __restrict__ out){
  __shared__ float ssum[256];
  int i = blockIdx.x;
  const float* hr = hiddenp + (size_t)i*H_;
  float ps = 0.f;
  for (int j = threadIdx.x; j < H_; j += 256) ps += hr[j]*Us[j];
  ssum[threadIdx.x] = ps; __syncthreads();
  for (int s = 128; s > 0; s >>= 1){
    if (threadIdx.x < s) ssum[threadIdx.x] += ssum[threadIdx.x+s];
    __syncthreads();
  }
  if (threadIdx.x == 0){
    float pl = ssum[0] + bs[0];
    float tgt = (float)p_tgt[i];
    float loss = fmaxf(pl, 0.f) + log1pf(expf(-fabsf(pl))) - pl*tgt;
    atomicAdd(out+1, loss * (1.0f/B_));
    int pred = (pl > 0.f) ? 1 : 0;
    atomicAdd(out+3, (pred == p_tgt[i]) ? (1.0f/(float)NPROWS) : 0.f);
  }
}

extern "C" void kernel_launch(void* const* d_in, const int* in_sizes, int n_in,
                              void* d_out, int out_size, void* d_ws, size_t ws_size,
                              hipStream_t stream){
  const float* tree_vec = (const float*)d_in[0];
  const float* emb  = (const float*)d_in[1];
  const float* Wz   = (const float*)d_in[2];
  const float* bz   = (const float*)d_in[3];
  const float* Wh   = (const float*)d_in[4];
  const float* bh   = (const float*)d_in[5];
  const float* Wr   = (const float*)d_in[6];
  const float* Ur   = (const float*)d_in[7];
  const float* br   = (const float*)d_in[8];
  const float* Ww   = (const float*)d_in[9];
  const float* bw   = (const float*)d_in[10];
  const float* Uw   = (const float*)d_in[11];
  const float* bu   = (const float*)d_in[12];
  const float* Wo   = (const float*)d_in[13];
  const float* bo   = (const float*)d_in[14];
  const float* Us   = (const float*)d_in[15];
  const float* bs   = (const float*)d_in[16];
  const int* wid      = (const int*)d_in[17];
  const int* root_ids = (const int*)d_in[18];
  const int* edge_src = (const int*)d_in[19];
  const int* edge_dst = (const int*)d_in[20];
  const int* edge_pred= (const int*)d_in[21];
  const int* node_in  = (const int*)d_in[22];
  const int* step_eid = (const int*)d_in[23];
  const int* step_v   = (const int*)d_in[24];
  const int* q_rows   = (const int*)d_in[25];
  const int* q_tgt    = (const int*)d_in[26];
  const int* p_tgt    = (const int*)d_in[27];
  int P  = in_sizes[21] / NEDGES;
  int Dn = in_sizes[22] / NNODES;
  int nq = in_sizes[25];

  char* ws = (char*)d_ws;
  size_t off = 0;
  auto alloc = [&](size_t bytes){ void* p = ws + off; off += (bytes + 255) & ~255ull; return p; };
  float* x       = (float*)alloc((size_t)NNODES*H_*4);
  float* h_steps = (float*)alloc((size_t)T_*B_*H_*4);
  size_t Roff = off;
  float* m  = (float*)alloc((size_t)(NEDGES+1)*H_*4);
  float* rm = (float*)alloc((size_t)(NEDGES+1)*H_*4);

  hipMemsetAsync(m,  0, (size_t)(NEDGES+1)*H_*4, stream);
  hipMemsetAsync(rm, 0, (size_t)(NEDGES+1)*H_*4, stream);
  hipMemsetAsync(d_out, 0, (size_t)out_size*sizeof(float), stream);

  k_gather_x<<<NNODES, 256, 0, stream>>>(emb, wid, x);

  ScanParams sp;
  sp.x = x; sp.Wz = Wz; sp.bz = bz; sp.Wh = Wh; sp.bh = bh;
  sp.Wr = Wr; sp.Ur = Ur; sp.br = br;
  sp.edge_src = edge_src; sp.edge_dst = edge_dst; sp.edge_pred = edge_pred;
  sp.node_in = node_in; sp.step_eid = step_eid; sp.step_v = step_v;
  sp.m = m; sp.rm = rm; sp.h_steps = h_steps;
  sp.P = (P > MAXP) ? MAXP : P; sp.Dn = (Dn > MAXD) ? MAXD : Dn;
  void* kargs[] = { &sp };
  hipLaunchCooperativeKernel(k_scan, dim3(SCAN_GRID), dim3(256), kargs, 0, stream);

  // Final-phase buffers aliased over dead m/rm region
  float* hiddenq = (float*)(ws + Roff);
  float* logitsq = hiddenq + (size_t)nq*H_;
  // q hidden: [nq, 506] @ [506, 450], relu
  k_mm64<<<dim3((H_+63)/64, (nq+63)/64), 256, 0, stream>>>(nq, H_, H_+L_, 0, 1,
      nullptr, Ww, bw, hiddenq, x, h_steps, tree_vec, q_rows, root_ids, step_v);
  // q logits: [nq, 450] @ [450, 780]
  k_mm64<<<dim3((V_+63)/64, (nq+63)/64), 256, 0, stream>>>(nq, V_, H_, 2, 0,
      hiddenq, Wo, bo, logitsq, x, h_steps, tree_vec, q_rows, root_ids, step_v);
  k_qreduce<<<nq, 256, 0, stream>>>(logitsq, q_tgt, nq, (float*)d_out);
  // p hidden: [19968, 956] @ [956, 450], relu  (reuses R region; q logits live after it? no - q done)
  float* hiddenp = (float*)(ws + Roff);
  k_mm64<<<dim3((H_+63)/64, (NPROWS+63)/64), 256, 0, stream>>>(NPROWS, H_, 2*H_+L_, 1, 1,
      nullptr, Uw, bu, hiddenp, x, h_steps, tree_vec, q_rows, root_ids, step_v);
  k_preduce<<<NPROWS, 256, 0, stream>>>(hiddenp, Us, bs, p_tgt, (float*)d_out);
}

// Round 3
// 3916.429 us; speedup vs baseline: 3.7195x; 3.7195x over previous
//
#include <hip/hip_runtime.h>
#include <math.h>

#define B_ 512
#define N_ 20
#define H_ 450
#define L_ 56
#define V_ 780
#define T_ 38
#define NNODES (B_*N_)        // 10240
#define NEDGES (B_*2*(N_-1))  // 19456
#define NPROWS ((T_+1)*B_)    // 19968
#define MAXP 8
#define MAXD 8
#define KP 928                // padded K for scan GEMMs (900 -> 928)

typedef __attribute__((ext_vector_type(8))) short bf16x8;
typedef __attribute__((ext_vector_type(4))) float f32x4;

__device__ __forceinline__ float sigmoidf_(float v){ return 1.0f/(1.0f+expf(-v)); }

// f32 -> bf16 (RNE)
__device__ __forceinline__ unsigned short f2b(float x){
  unsigned int u = __float_as_uint(x);
  unsigned int r = (u + 0x7fffu + ((u >> 16) & 1u)) >> 16;
  return (unsigned short)r;
}

// ---------------------------------------------------------------------------
// x[i][:] = emb[wid[i]][:]  (f32)
__global__ void k_gather_x(const float* __restrict__ emb, const int* __restrict__ wid,
                           float* __restrict__ x){
  int i = blockIdx.x; int w = wid[i];
  for (int j = threadIdx.x; j < H_; j += blockDim.x)
    x[(size_t)i*H_+j] = emb[(size_t)w*H_+j];
}

// Transpose+convert weight to K-major bf16 with zero padding.
// dst[c][k] (c = blockIdx.x < Npad64, k < Kpad). W stacked: k<Ksplit from W1, else W2.
__global__ void k_wt(const float* __restrict__ W1, const float* __restrict__ W2,
                     int Ksplit, int Kact, int Nact, unsigned short* __restrict__ dst, int Kpad){
  int c = blockIdx.x;
  unsigned short* drow = dst + (size_t)c*Kpad;
  for (int k = threadIdx.x; k < Kpad; k += blockDim.x){
    float v = 0.f;
    if (c < Nact && k < Kact)
      v = (k < Ksplit) ? W1[(size_t)k*Nact + c] : W2[(size_t)(k-Ksplit)*Nact + c];
    drow[k] = f2b(v);
  }
}

// ---------------------------------------------------------------------------
// Per-step A-matrix prep: A1=[sx|s], A2=[sx|arm] (bf16), A3[:,0:450]=dx; SBUF=s (f32)
__global__ void k_prep2(const float* __restrict__ x, const float* __restrict__ m_,
    const float* __restrict__ rm,
    const int* __restrict__ edge_src, const int* __restrict__ edge_dst,
    const int* __restrict__ edge_pred, const int* __restrict__ step_eid, int t, int P,
    unsigned short* __restrict__ A1b, unsigned short* __restrict__ A2b,
    unsigned short* __restrict__ A3b, float* __restrict__ SBUF){
  int b = blockIdx.x;
  int eid = step_eid[t*B_+b];
  int soff = edge_src[eid]*H_, doff = edge_dst[eid]*H_;
  int poff[MAXP];
  for (int q = 0; q < P; ++q) poff[q] = edge_pred[eid*P+q]*H_;
  for (int j = threadIdx.x; j < H_; j += blockDim.x){
    float sx = x[soff+j];
    unsigned short sb = f2b(sx);
    A1b[(size_t)b*KP + j] = sb;
    A2b[(size_t)b*KP + j] = sb;
    A3b[(size_t)b*KP + j] = f2b(x[doff+j]);
    float s = 0.f, ar = 0.f;
    for (int q = 0; q < P; ++q){ s += m_[poff[q]+j]; ar += rm[poff[q]+j]; }
    SBUF[(size_t)b*H_ + j] = s;
    A1b[(size_t)b*KP + 450 + j] = f2b(s);
    A2b[(size_t)b*KP + 450 + j] = f2b(ar);
  }
}

// ---------------------------------------------------------------------------
// MFMA tile core: 64x64 tile, 4 waves (2x2), BK=32, K-major bf16 A[M][K], BT[N][K].
// LDS rows padded to 40 shorts (80B) -> 2-way max bank aliasing (free).
__device__ __forceinline__ void mfma_tile_core(
    const unsigned short* __restrict__ A, const unsigned short* __restrict__ BT,
    int K, int gr0, int gc0, int tid,
    unsigned short* __restrict__ As, unsigned short* __restrict__ Bs,
    f32x4 (&acc)[2][2])
{
  const int lane = tid & 63;
  const int w = tid >> 6, wr = w >> 1, wc = w & 1;
  const int l15 = lane & 15, kh = lane >> 4;
  const int sr = tid >> 2, sj = (tid & 3) * 8;
  const size_t arow = (size_t)(gr0 + sr) * K;
  const size_t brow = (size_t)(gc0 + sr) * K;
  for (int kt = 0; kt < K; kt += 32){
    __syncthreads();
    *(float4*)&As[sr*40 + sj] = *(const float4*)&A[arow + kt + sj];
    *(float4*)&Bs[sr*40 + sj] = *(const float4*)&BT[brow + kt + sj];
    __syncthreads();
    bf16x8 a0 = *(const bf16x8*)&As[(wr*32      + l15)*40 + kh*8];
    bf16x8 a1 = *(const bf16x8*)&As[(wr*32 + 16 + l15)*40 + kh*8];
    bf16x8 b0 = *(const bf16x8*)&Bs[(wc*32      + l15)*40 + kh*8];
    bf16x8 b1 = *(const bf16x8*)&Bs[(wc*32 + 16 + l15)*40 + kh*8];
    acc[0][0] = __builtin_amdgcn_mfma_f32_16x16x32_bf16(a0,b0,acc[0][0],0,0,0);
    acc[0][1] = __builtin_amdgcn_mfma_f32_16x16x32_bf16(a0,b1,acc[0][1],0,0,0);
    acc[1][0] = __builtin_amdgcn_mfma_f32_16x16x32_bf16(a1,b0,acc[1][0],0,0,0);
    acc[1][1] = __builtin_amdgcn_mfma_f32_16x16x32_bf16(a1,b1,acc[1][1],0,0,0);
  }
}

// Gate: z=sigmoid(A1@Wz+bz), th=tanh(A2@Wh+bh), m_new=(1-z)*s+z*th
// writes m[eid] (f32) and A3b[:,450:900] (bf16)
__global__ __launch_bounds__(256) void k_gate_mfma(
    const unsigned short* __restrict__ A1b, const unsigned short* __restrict__ A2b,
    const unsigned short* __restrict__ WzT, const unsigned short* __restrict__ WhT,
    const float* __restrict__ bz, const float* __restrict__ bh,
    const float* __restrict__ SBUF, const int* __restrict__ step_eid, int t,
    float* __restrict__ m_, unsigned short* __restrict__ A3b)
{
  __shared__ unsigned short As1[64*40], As2[64*40], Bs1[64*40], Bs2[64*40];
  __shared__ int s_eid[64];
  const int tid = threadIdx.x;
  const int gr0 = blockIdx.y*64, gc0 = blockIdx.x*64;
  if (tid < 64) s_eid[tid] = step_eid[t*B_ + gr0 + tid];
  f32x4 accZ[2][2] = {}, accH[2][2] = {};
  const int lane = tid & 63;
  const int w = tid >> 6, wr = w >> 1, wc = w & 1;
  const int l15 = lane & 15, kh = lane >> 4;
  const int sr = tid >> 2, sj = (tid & 3) * 8;
  const size_t arow = (size_t)(gr0 + sr) * KP;
  const size_t brow = (size_t)(gc0 + sr) * KP;
  for (int kt = 0; kt < KP; kt += 32){
    __syncthreads();
    *(float4*)&As1[sr*40 + sj] = *(const float4*)&A1b[arow + kt + sj];
    *(float4*)&As2[sr*40 + sj] = *(const float4*)&A2b[arow + kt + sj];
    *(float4*)&Bs1[sr*40 + sj] = *(const float4*)&WzT[brow + kt + sj];
    *(float4*)&Bs2[sr*40 + sj] = *(const float4*)&WhT[brow + kt + sj];
    __syncthreads();
    bf16x8 a10 = *(const bf16x8*)&As1[(wr*32      + l15)*40 + kh*8];
    bf16x8 a11 = *(const bf16x8*)&As1[(wr*32 + 16 + l15)*40 + kh*8];
    bf16x8 a20 = *(const bf16x8*)&As2[(wr*32      + l15)*40 + kh*8];
    bf16x8 a21 = *(const bf16x8*)&As2[(wr*32 + 16 + l15)*40 + kh*8];
    bf16x8 b10 = *(const bf16x8*)&Bs1[(wc*32      + l15)*40 + kh*8];
    bf16x8 b11 = *(const bf16x8*)&Bs1[(wc*32 + 16 + l15)*40 + kh*8];
    bf16x8 b20 = *(const bf16x8*)&Bs2[(wc*32      + l15)*40 + kh*8];
    bf16x8 b21 = *(const bf16x8*)&Bs2[(wc*32 + 16 + l15)*40 + kh*8];
    accZ[0][0] = __builtin_amdgcn_mfma_f32_16x16x32_bf16(a10,b10,accZ[0][0],0,0,0);
    accZ[0][1] = __builtin_amdgcn_mfma_f32_16x16x32_bf16(a10,b11,accZ[0][1],0,0,0);
    accZ[1][0] = __builtin_amdgcn_mfma_f32_16x16x32_bf16(a11,b10,accZ[1][0],0,0,0);
    accZ[1][1] = __builtin_amdgcn_mfma_f32_16x16x32_bf16(a11,b11,accZ[1][1],0,0,0);
    accH[0][0] = __builtin_amdgcn_mfma_f32_16x16x32_bf16(a20,b20,accH[0][0],0,0,0);
    accH[0][1] = __builtin_amdgcn_mfma_f32_16x16x32_bf16(a20,b21,accH[0][1],0,0,0);
    accH[1][0] = __builtin_amdgcn_mfma_f32_16x16x32_bf16(a21,b20,accH[1][0],0,0,0);
    accH[1][1] = __builtin_amdgcn_mfma_f32_16x16x32_bf16(a21,b21,accH[1][1],0,0,0);
  }
  #pragma unroll
  for (int mi = 0; mi < 2; ++mi){
    #pragma unroll
    for (int n = 0; n < 2; ++n){
      int c = gc0 + wc*32 + n*16 + l15;
      if (c >= H_) continue;
      float bzc = bz[c], bhc = bh[c];
      #pragma unroll
      for (int reg = 0; reg < 4; ++reg){
        int rl = wr*32 + mi*16 + kh*4 + reg;   // local row
        int r  = gr0 + rl;
        float z  = sigmoidf_(accZ[mi][n][reg] + bzc);
        float th = tanhf(accH[mi][n][reg] + bhc);
        float s  = SBUF[(size_t)r*H_ + c];
        float mn = (1.f - z)*s + z*th;
        int eid = s_eid[rl];
        m_[(size_t)eid*H_ + c] = mn;
        A3b[(size_t)r*KP + 450 + c] = f2b(mn);
      }
    }
  }
}

// Rgate: r=sigmoid(A3@[Wr;Ur]+br); rm[eid]=r*m_new; h=sum m[node_in[v]] -> hb (bf16)
__global__ __launch_bounds__(256) void k_rgate_mfma(
    const unsigned short* __restrict__ A3b, const unsigned short* __restrict__ WrUrT,
    const float* __restrict__ br, const int* __restrict__ step_eid,
    const int* __restrict__ step_v, const int* __restrict__ node_in, int t, int Dn,
    const float* __restrict__ m_, float* __restrict__ rm, unsigned short* __restrict__ hb)
{
  __shared__ unsigned short As[64*40], Bs[64*40];
  __shared__ int s_eid[64];
  __shared__ int s_noff[64][MAXD];
  const int tid = threadIdx.x;
  const int gr0 = blockIdx.y*64, gc0 = blockIdx.x*64;
  if (tid < 64){
    s_eid[tid] = step_eid[t*B_ + gr0 + tid];
    int v = step_v[t*B_ + gr0 + tid];
    for (int d = 0; d < Dn; ++d) s_noff[tid][d] = node_in[v*Dn + d]*H_;
  }
  f32x4 acc[2][2] = {};
  mfma_tile_core(A3b, WrUrT, KP, gr0, gc0, tid, As, Bs, acc);
  const int lane = tid & 63;
  const int w = tid >> 6, wr = w >> 1, wc = w & 1;
  const int l15 = lane & 15, kh = lane >> 4;
  #pragma unroll
  for (int mi = 0; mi < 2; ++mi){
    #pragma unroll
    for (int n = 0; n < 2; ++n){
      int c = gc0 + wc*32 + n*16 + l15;
      if (c >= H_) continue;
      float brc = br[c];
      #pragma unroll
      for (int reg = 0; reg < 4; ++reg){
        int rl = wr*32 + mi*16 + kh*4 + reg;
        int r  = gr0 + rl;
        float r_ = sigmoidf_(acc[mi][n][reg] + brc);
        int eid = s_eid[rl];
        float mn = m_[(size_t)eid*H_ + c];
        rm[(size_t)eid*H_ + c] = r_*mn;
        float h = 0.f;
        for (int d = 0; d < Dn; ++d) h += m_[s_noff[rl][d] + c];
        hb[(size_t)(t*B_ + r)*H_ + c] = f2b(h);
      }
    }
  }
}

// Head GEMM: C = act(A@B + bias); optional f32 and/or bf16 stores.
__global__ __launch_bounds__(256) void k_head_mfma(
    const unsigned short* __restrict__ A, const unsigned short* __restrict__ BT, int K,
    const float* __restrict__ bias, int Nact, int relu,
    float* __restrict__ outF, int ldF, unsigned short* __restrict__ outB, int ldB)
{
  __shared__ unsigned short As[64*40], Bs[64*40];
  const int tid = threadIdx.x;
  const int gr0 = blockIdx.y*64, gc0 = blockIdx.x*64;
  f32x4 acc[2][2] = {};
  mfma_tile_core(A, BT, K, gr0, gc0, tid, As, Bs, acc);
  const int lane = tid & 63;
  const int w = tid >> 6, wr = w >> 1, wc = w & 1;
  const int l15 = lane & 15, kh = lane >> 4;
  #pragma unroll
  for (int mi = 0; mi < 2; ++mi){
    #pragma unroll
    for (int n = 0; n < 2; ++n){
      int c = gc0 + wc*32 + n*16 + l15;
      if (c >= Nact) continue;
      float bc = bias[c];
      #pragma unroll
      for (int reg = 0; reg < 4; ++reg){
        int r = gr0 + wr*32 + mi*16 + kh*4 + reg;
        float v = acc[mi][n][reg] + bc;
        if (relu) v = fmaxf(v, 0.f);
        if (outF) outF[(size_t)r*ldF + c] = v;
        if (outB) outB[(size_t)r*ldB + c] = f2b(v);
      }
    }
  }
}

// ---------------------------------------------------------------------------
// Builders for head A matrices (bf16, padded; pads pre-zeroed by memset)
__global__ void k_build_Aq(const unsigned short* __restrict__ hb,
    const float* __restrict__ tree_vec, const int* __restrict__ q_rows,
    unsigned short* __restrict__ Aq){
  int i = blockIdx.x;
  int row = q_rows[i]; int b = row & (B_-1);
  unsigned short* dst = Aq + (size_t)i*512;
  for (int k = threadIdx.x; k < 506; k += blockDim.x){
    unsigned short v;
    if (k < H_) v = (row < B_) ? 0 : hb[(size_t)(row-B_)*H_ + k];
    else        v = f2b(tree_vec[b*L_ + (k - H_)]);
    dst[k] = v;
  }
}

__global__ void k_build_Ap(const unsigned short* __restrict__ hb,
    const float* __restrict__ x, const float* __restrict__ tree_vec,
    const int* __restrict__ root_ids, const int* __restrict__ step_v,
    unsigned short* __restrict__ Ap){
  int i = blockIdx.x; int b = i & (B_-1);
  unsigned short* dst = Ap + (size_t)i*960;
  for (int k = threadIdx.x; k < 956; k += blockDim.x){
    unsigned short v;
    if (k < H_){
      int xn = (i < B_) ? root_ids[b] : step_v[i - B_];
      v = f2b(x[(size_t)xn*H_ + k]);
    } else if (k < 2*H_){
      v = (i < B_) ? 0 : hb[(size_t)(i-B_)*H_ + (k - H_)];
    } else {
      v = f2b(tree_vec[b*L_ + (k - 2*H_)]);
    }
    dst[k] = v;
  }
}

// ---------------------------------------------------------------------------
// Per-row: lse, argmax (first occurrence), target logit -> q_loss, q_acc
__global__ __launch_bounds__(256) void k_qreduce(const float* __restrict__ logits,
    const int* __restrict__ q_tgt, int nq, float* __restrict__ out){
  __shared__ float smax[256]; __shared__ int sidx[256]; __shared__ float ssum[256];
  int i = blockIdx.x;
  const float* lr = logits + (size_t)i*V_;
  float mx = -INFINITY; int mi = 0;
  for (int j = threadIdx.x; j < V_; j += 256){
    float v = lr[j];
    if (v > mx){ mx = v; mi = j; }
  }
  smax[threadIdx.x] = mx; sidx[threadIdx.x] = mi;
  __syncthreads();
  for (int s = 128; s > 0; s >>= 1){
    if (threadIdx.x < s){
      float v2 = smax[threadIdx.x+s]; int i2 = sidx[threadIdx.x+s];
      float v1 = smax[threadIdx.x];   int i1 = sidx[threadIdx.x];
      if (v2 > v1 || (v2 == v1 && i2 < i1)){ smax[threadIdx.x] = v2; sidx[threadIdx.x] = i2; }
    }
    __syncthreads();
  }
  float gmax = smax[0]; int gidx = sidx[0];
  float ps = 0.f;
  for (int j = threadIdx.x; j < V_; j += 256) ps += expf(lr[j]-gmax);
  ssum[threadIdx.x] = ps; __syncthreads();
  for (int s = 128; s > 0; s >>= 1){
    if (threadIdx.x < s) ssum[threadIdx.x] += ssum[threadIdx.x+s];
    __syncthreads();
  }
  if (threadIdx.x == 0){
    float lse = gmax + logf(ssum[0]);
    int tg = q_tgt[i];
    atomicAdd(out+0, (lse - lr[tg]) * (1.0f/B_));
    atomicAdd(out+2, (gidx == tg) ? (1.0f/(float)nq) : 0.f);
  }
}

// Per-row: p_logit = hidden.Us + bs -> BCE loss + acc
__global__ __launch_bounds__(256) void k_preduce(const float* __restrict__ hiddenp,
    const float* __restrict__ Us, const float* __restrict__ bs,
    const int* __restrict__ p_tgt, float* __restrict__ out){
  __shared__ float ssum[256];
  int i = blockIdx.x;
  const float* hr = hiddenp + (size_t)i*H_;
  float ps = 0.f;
  for (int j = threadIdx.x; j < H_; j += 256) ps += hr[j]*Us[j];
  ssum[threadIdx.x] = ps; __syncthreads();
  for (int s = 128; s > 0; s >>= 1){
    if (threadIdx.x < s) ssum[threadIdx.x] += ssum[threadIdx.x+s];
    __syncthreads();
  }
  if (threadIdx.x == 0){
    float pl = ssum[0] + bs[0];
    float tgt = (float)p_tgt[i];
    float loss = fmaxf(pl, 0.f) + log1pf(expf(-fabsf(pl))) - pl*tgt;
    atomicAdd(out+1, loss * (1.0f/B_));
    int pred = (pl > 0.f) ? 1 : 0;
    atomicAdd(out+3, (pred == p_tgt[i]) ? (1.0f/(float)NPROWS) : 0.f);
  }
}

// ---------------------------------------------------------------------------
extern "C" void kernel_launch(void* const* d_in, const int* in_sizes, int n_in,
                              void* d_out, int out_size, void* d_ws, size_t ws_size,
                              hipStream_t stream){
  const float* tree_vec = (const float*)d_in[0];
  const float* emb  = (const float*)d_in[1];
  const float* Wz   = (const float*)d_in[2];
  const float* bz   = (const float*)d_in[3];
  const float* Wh   = (const float*)d_in[4];
  const float* bh   = (const float*)d_in[5];
  const float* Wr   = (const float*)d_in[6];
  const float* Ur   = (const float*)d_in[7];
  const float* br   = (const float*)d_in[8];
  const float* Ww   = (const float*)d_in[9];
  const float* bw   = (const float*)d_in[10];
  const float* Uw   = (const float*)d_in[11];
  const float* bu   = (const float*)d_in[12];
  const float* Wo   = (const float*)d_in[13];
  const float* bo   = (const float*)d_in[14];
  const float* Us   = (const float*)d_in[15];
  const float* bs   = (const float*)d_in[16];
  const int* wid      = (const int*)d_in[17];
  const int* root_ids = (const int*)d_in[18];
  const int* edge_src = (const int*)d_in[19];
  const int* edge_dst = (const int*)d_in[20];
  const int* edge_pred= (const int*)d_in[21];
  const int* node_in  = (const int*)d_in[22];
  const int* step_eid = (const int*)d_in[23];
  const int* step_v   = (const int*)d_in[24];
  const int* q_rows   = (const int*)d_in[25];
  const int* q_tgt    = (const int*)d_in[26];
  const int* p_tgt    = (const int*)d_in[27];
  int P  = in_sizes[21] / NEDGES;  if (P > MAXP) P = MAXP;
  int Dn = in_sizes[22] / NNODES;  if (Dn > MAXD) Dn = MAXD;
  int nq = in_sizes[25];           // 10240

  char* ws = (char*)d_ws;
  // --- fixed layout ---
  const size_t X_OFF   = 0;                        // f32 [10240][450] = 18,432,000
  const size_t HB_OFF  = 18432000;                 // bf16 [T*B][450]  = 17,510,400
  const size_t M_OFF   = 35942400;                 // f32 [(E+1)][450] = 35,022,600 (pad 35,022,848)
  const size_t RM_OFF  = M_OFF + 35022848;
  const size_t A_OFF   = RM_OFF + 35022848;        // = 105,988,096
  const size_t A1B_OFF = A_OFF;                    // bf16 [512][928] = 950,272
  const size_t A2B_OFF = A1B_OFF + 950272;
  const size_t A3B_OFF = A2B_OFF + 950272;
  const size_t SB_OFF  = A3B_OFF + 950272;         // f32 [512][450] = 921,600
  const size_t WZT_OFF = SB_OFF + 921600;          // bf16 [512][928]
  const size_t WHT_OFF = WZT_OFF + 950272;
  const size_t WRT_OFF = WHT_OFF + 950272;
  const size_t WWT_OFF = WRT_OFF + 950272;         // bf16 [512][512] = 524,288
  const size_t UWT_OFF = WWT_OFF + 524288;         // bf16 [512][960] = 983,040
  const size_t WOT_OFF = UWT_OFF + 983040;         // bf16 [832][512] = 851,968
  // overlay (dead m/rm region after scan):
  const size_t AQ_OFF  = M_OFF;                    // bf16 [10240][512] = 10,485,760
  const size_t LQ_OFF  = M_OFF + 10485760;         // f32 [10240][780] = 31,948,800
  const size_t HQB_OFF = M_OFF + 42434560;         // bf16 [10240][512] = 10,485,760
  const size_t AP_OFF  = M_OFF;                    // bf16 [19968][960] = 38,338,560
  const size_t HP_OFF  = 0;                        // f32 [19968][450] = 35,942,400 (over x+hb)

  float* x  = (float*)(ws + X_OFF);
  unsigned short* hb = (unsigned short*)(ws + HB_OFF);
  float* m_ = (float*)(ws + M_OFF);
  float* rm = (float*)(ws + RM_OFF);
  unsigned short* A1b = (unsigned short*)(ws + A1B_OFF);
  unsigned short* A2b = (unsigned short*)(ws + A2B_OFF);
  unsigned short* A3b = (unsigned short*)(ws + A3B_OFF);
  float* SBUF = (float*)(ws + SB_OFF);
  unsigned short* WzT = (unsigned short*)(ws + WZT_OFF);
  unsigned short* WhT = (unsigned short*)(ws + WHT_OFF);
  unsigned short* WrUrT = (unsigned short*)(ws + WRT_OFF);
  unsigned short* WwT = (unsigned short*)(ws + WWT_OFF);
  unsigned short* UwT = (unsigned short*)(ws + UWT_OFF);
  unsigned short* WoT = (unsigned short*)(ws + WOT_OFF);

  // zero init: m, rm (incl. sentinel row), A1b..A3b (K-pad cols), out
  hipMemsetAsync(ws + M_OFF, 0, 2*35022848ull, stream);
  hipMemsetAsync(ws + A1B_OFF, 0, 3*950272ull, stream);
  hipMemsetAsync(d_out, 0, (size_t)out_size*sizeof(float), stream);

  k_gather_x<<<NNODES, 256, 0, stream>>>(emb, wid, x);

  // weight transpose+convert (bf16, K-major, zero-padded)
  k_wt<<<512, 256, 0, stream>>>(Wz, Wz, 900, 900, 450, WzT, KP);
  k_wt<<<512, 256, 0, stream>>>(Wh, Wh, 900, 900, 450, WhT, KP);
  k_wt<<<512, 256, 0, stream>>>(Wr, Ur, 450, 900, 450, WrUrT, KP);
  k_wt<<<512, 256, 0, stream>>>(Ww, Ww, 506, 506, 450, WwT, 512);
  k_wt<<<512, 256, 0, stream>>>(Uw, Uw, 956, 956, 450, UwT, 960);
  k_wt<<<832, 256, 0, stream>>>(Wo, Wo, 450, 450, 780, WoT, 512);

  // ---- 38-step scan: prep -> gate GEMM -> rgate GEMM (kernel boundaries = deps) ----
  dim3 gScan(8, 8);   // ceil(450/64)=8 cols x 512/64=8 rows
  for (int t = 0; t < T_; ++t){
    k_prep2<<<B_, 256, 0, stream>>>(x, m_, rm, edge_src, edge_dst, edge_pred,
                                    step_eid, t, P, A1b, A2b, A3b, SBUF);
    k_gate_mfma<<<gScan, 256, 0, stream>>>(A1b, A2b, WzT, WhT, bz, bh, SBUF,
                                           step_eid, t, m_, A3b);
    k_rgate_mfma<<<gScan, 256, 0, stream>>>(A3b, WrUrT, br, step_eid, step_v,
                                            node_in, t, Dn, m_, rm, hb);
  }

  // ---- heads (overlay region; m/rm dead now) ----
  unsigned short* Aq  = (unsigned short*)(ws + AQ_OFF);
  float* logitsq      = (float*)(ws + LQ_OFF);
  unsigned short* hqb = (unsigned short*)(ws + HQB_OFF);
  hipMemsetAsync(ws + M_OFF, 0, 52920320ull, stream);   // Aq+logits+hqb (pads -> 0)

  k_build_Aq<<<nq, 256, 0, stream>>>(hb, tree_vec, q_rows, Aq);
  // q hidden: [10240,512]@[512 ->450], relu, bf16 out
  k_head_mfma<<<dim3(8, nq/64), 256, 0, stream>>>(Aq, WwT, 512, bw, H_, 1,
      nullptr, 0, hqb, 512);
  // q logits: [10240,512]@[512 ->780], f32 out
  k_head_mfma<<<dim3(13, nq/64), 256, 0, stream>>>(hqb, WoT, 512, bo, V_, 0,
      logitsq, V_, nullptr, 0);
  k_qreduce<<<nq, 256, 0, stream>>>(logitsq, q_tgt, nq, (float*)d_out);

  unsigned short* Ap = (unsigned short*)(ws + AP_OFF);
  float* hiddenp     = (float*)(ws + HP_OFF);
  hipMemsetAsync(ws + AP_OFF, 0, 38338560ull, stream);  // Ap (pads -> 0)
  k_build_Ap<<<NPROWS, 256, 0, stream>>>(hb, x, tree_vec, root_ids, step_v, Ap);
  // p hidden: [19968,960]@[960 ->450], relu, f32 out
  k_head_mfma<<<dim3(8, NPROWS/64), 256, 0, stream>>>(Ap, UwT, 960, bu, H_, 1,
      hiddenp, H_, nullptr, 0);
  k_preduce<<<NPROWS, 256, 0, stream>>>(hiddenp, Us, bs, p_tgt, (float*)d_out);
}

// Round 4
// 3131.391 us; speedup vs baseline: 4.6520x; 1.2507x over previous
//
#include <hip/hip_runtime.h>
#include <math.h>

#define B_ 512
#define N_ 20
#define H_ 450
#define L_ 56
#define V_ 780
#define T_ 38
#define NNODES (B_*N_)        // 10240
#define NEDGES (B_*2*(N_-1))  // 19456
#define NPROWS ((T_+1)*B_)    // 19968
#define MAXP 8
#define MAXD 8
#define KP 928                // padded K for scan GEMMs (900 -> 928)

typedef __attribute__((ext_vector_type(8))) short bf16x8;
typedef __attribute__((ext_vector_type(4))) float f32x4;

__device__ __forceinline__ float sigmoidf_(float v){ return 1.0f/(1.0f+expf(-v)); }

// f32 -> bf16 (RNE)
__device__ __forceinline__ unsigned short f2b(float x){
  unsigned int u = __float_as_uint(x);
  unsigned int r = (u + 0x7fffu + ((u >> 16) & 1u)) >> 16;
  return (unsigned short)r;
}
__device__ __forceinline__ unsigned int pack2(float lo, float hi){
  return (unsigned int)f2b(lo) | ((unsigned int)f2b(hi) << 16);
}

// ---------------------------------------------------------------------------
// x[i][:] = emb[wid[i]][:]  (f32), one wave per row, float2
__global__ __launch_bounds__(256) void k_gather_x(const float* __restrict__ emb,
    const int* __restrict__ wid, float* __restrict__ x){
  int w = blockIdx.x*4 + (threadIdx.x>>6), lane = threadIdx.x & 63;
  if (w >= NNODES) return;
  const float2* src = (const float2*)(emb + (size_t)wid[w]*H_);
  float2* dst = (float2*)(x + (size_t)w*H_);
  for (int j2 = lane; j2 < 225; j2 += 64) dst[j2] = src[j2];
}

// Transpose+convert weight to K-major bf16 with zero padding.
__global__ void k_wt(const float* __restrict__ W1, const float* __restrict__ W2,
                     int Ksplit, int Kact, int Nact, unsigned short* __restrict__ dst, int Kpad){
  int c = blockIdx.x;
  unsigned short* drow = dst + (size_t)c*Kpad;
  for (int k = threadIdx.x; k < Kpad; k += blockDim.x){
    float v = 0.f;
    if (c < Nact && k < Kact)
      v = (k < Ksplit) ? W1[(size_t)k*Nact + c] : W2[(size_t)(k-Ksplit)*Nact + c];
    drow[k] = f2b(v);
  }
}

// ---------------------------------------------------------------------------
// Per-step A-matrix prep: A1=[sx|s], A2=[sx|arm] (bf16), A3[:,0:450]=dx; SBUF=s (f32)
// grid (B_, 4) x 64 threads; each thread does one float2 column pair.
__global__ __launch_bounds__(64) void k_prep2(const float* __restrict__ x,
    const float* __restrict__ m_, const float* __restrict__ rm,
    const int* __restrict__ edge_src, const int* __restrict__ edge_dst,
    const int* __restrict__ edge_pred, const int* __restrict__ step_eid, int t, int P,
    unsigned short* __restrict__ A1b, unsigned short* __restrict__ A2b,
    unsigned short* __restrict__ A3b, float* __restrict__ SBUF){
  int b = blockIdx.x;
  int j2 = blockIdx.y*64 + threadIdx.x;
  if (j2 >= 225) return;
  int eid = step_eid[t*B_+b];
  int soff = edge_src[eid]*H_, doff = edge_dst[eid]*H_;
  int poff[MAXP];
  for (int q = 0; q < P; ++q) poff[q] = edge_pred[eid*P+q]*H_;
  int j = 2*j2;
  float2 sx = *(const float2*)(x + soff + j);
  float2 dx = *(const float2*)(x + doff + j);
  float2 s = {0.f,0.f}, ar = {0.f,0.f};
  for (int q = 0; q < P; ++q){
    float2 mv = *(const float2*)(m_ + poff[q] + j);
    float2 rv = *(const float2*)(rm + poff[q] + j);
    s.x += mv.x; s.y += mv.y; ar.x += rv.x; ar.y += rv.y;
  }
  unsigned int sxp = pack2(sx.x, sx.y);
  ((unsigned int*)(A1b + (size_t)b*KP))[j2] = sxp;
  ((unsigned int*)(A2b + (size_t)b*KP))[j2] = sxp;
  ((unsigned int*)(A3b + (size_t)b*KP))[j2] = pack2(dx.x, dx.y);
  *(float2*)(SBUF + (size_t)b*H_ + j) = s;
  ((unsigned int*)(A1b + (size_t)b*KP + 450))[j2] = pack2(s.x, s.y);
  ((unsigned int*)(A2b + (size_t)b*KP + 450))[j2] = pack2(ar.x, ar.y);
}

// ---------------------------------------------------------------------------
// MFMA tile core: 64x64 tile, 4 waves (2x2), BK=32, K-major bf16 A[M][K], BT[N][K].
__device__ __forceinline__ void mfma_tile_core(
    const unsigned short* __restrict__ A, const unsigned short* __restrict__ BT,
    int K, int gr0, int gc0, int tid,
    unsigned short* __restrict__ As, unsigned short* __restrict__ Bs,
    f32x4 (&acc)[2][2])
{
  const int lane = tid & 63;
  const int w = tid >> 6, wr = w >> 1, wc = w & 1;
  const int l15 = lane & 15, kh = lane >> 4;
  const int sr = tid >> 2, sj = (tid & 3) * 8;
  const size_t arow = (size_t)(gr0 + sr) * K;
  const size_t brow = (size_t)(gc0 + sr) * K;
  for (int kt = 0; kt < K; kt += 32){
    __syncthreads();
    *(float4*)&As[sr*40 + sj] = *(const float4*)&A[arow + kt + sj];
    *(float4*)&Bs[sr*40 + sj] = *(const float4*)&BT[brow + kt + sj];
    __syncthreads();
    bf16x8 a0 = *(const bf16x8*)&As[(wr*32      + l15)*40 + kh*8];
    bf16x8 a1 = *(const bf16x8*)&As[(wr*32 + 16 + l15)*40 + kh*8];
    bf16x8 b0 = *(const bf16x8*)&Bs[(wc*32      + l15)*40 + kh*8];
    bf16x8 b1 = *(const bf16x8*)&Bs[(wc*32 + 16 + l15)*40 + kh*8];
    acc[0][0] = __builtin_amdgcn_mfma_f32_16x16x32_bf16(a0,b0,acc[0][0],0,0,0);
    acc[0][1] = __builtin_amdgcn_mfma_f32_16x16x32_bf16(a0,b1,acc[0][1],0,0,0);
    acc[1][0] = __builtin_amdgcn_mfma_f32_16x16x32_bf16(a1,b0,acc[1][0],0,0,0);
    acc[1][1] = __builtin_amdgcn_mfma_f32_16x16x32_bf16(a1,b1,acc[1][1],0,0,0);
  }
}

// Gate: z=sigmoid(A1@Wz+bz), th=tanh(A2@Wh+bh), m_new=(1-z)*s+z*th
__global__ __launch_bounds__(256) void k_gate_mfma(
    const unsigned short* __restrict__ A1b, const unsigned short* __restrict__ A2b,
    const unsigned short* __restrict__ WzT, const unsigned short* __restrict__ WhT,
    const float* __restrict__ bz, const float* __restrict__ bh,
    const float* __restrict__ SBUF, const int* __restrict__ step_eid, int t,
    float* __restrict__ m_, unsigned short* __restrict__ A3b)
{
  __shared__ unsigned short As1[64*40], As2[64*40], Bs1[64*40], Bs2[64*40];
  __shared__ int s_eid[64];
  const int tid = threadIdx.x;
  const int gr0 = blockIdx.y*64, gc0 = blockIdx.x*64;
  if (tid < 64) s_eid[tid] = step_eid[t*B_ + gr0 + tid];
  f32x4 accZ[2][2] = {}, accH[2][2] = {};
  const int lane = tid & 63;
  const int w = tid >> 6, wr = w >> 1, wc = w & 1;
  const int l15 = lane & 15, kh = lane >> 4;
  const int sr = tid >> 2, sj = (tid & 3) * 8;
  const size_t arow = (size_t)(gr0 + sr) * KP;
  const size_t brow = (size_t)(gc0 + sr) * KP;
  for (int kt = 0; kt < KP; kt += 32){
    __syncthreads();
    *(float4*)&As1[sr*40 + sj] = *(const float4*)&A1b[arow + kt + sj];
    *(float4*)&As2[sr*40 + sj] = *(const float4*)&A2b[arow + kt + sj];
    *(float4*)&Bs1[sr*40 + sj] = *(const float4*)&WzT[brow + kt + sj];
    *(float4*)&Bs2[sr*40 + sj] = *(const float4*)&WhT[brow + kt + sj];
    __syncthreads();
    bf16x8 a10 = *(const bf16x8*)&As1[(wr*32      + l15)*40 + kh*8];
    bf16x8 a11 = *(const bf16x8*)&As1[(wr*32 + 16 + l15)*40 + kh*8];
    bf16x8 a20 = *(const bf16x8*)&As2[(wr*32      + l15)*40 + kh*8];
    bf16x8 a21 = *(const bf16x8*)&As2[(wr*32 + 16 + l15)*40 + kh*8];
    bf16x8 b10 = *(const bf16x8*)&Bs1[(wc*32      + l15)*40 + kh*8];
    bf16x8 b11 = *(const bf16x8*)&Bs1[(wc*32 + 16 + l15)*40 + kh*8];
    bf16x8 b20 = *(const bf16x8*)&Bs2[(wc*32      + l15)*40 + kh*8];
    bf16x8 b21 = *(const bf16x8*)&Bs2[(wc*32 + 16 + l15)*40 + kh*8];
    accZ[0][0] = __builtin_amdgcn_mfma_f32_16x16x32_bf16(a10,b10,accZ[0][0],0,0,0);
    accZ[0][1] = __builtin_amdgcn_mfma_f32_16x16x32_bf16(a10,b11,accZ[0][1],0,0,0);
    accZ[1][0] = __builtin_amdgcn_mfma_f32_16x16x32_bf16(a11,b10,accZ[1][0],0,0,0);
    accZ[1][1] = __builtin_amdgcn_mfma_f32_16x16x32_bf16(a11,b11,accZ[1][1],0,0,0);
    accH[0][0] = __builtin_amdgcn_mfma_f32_16x16x32_bf16(a20,b20,accH[0][0],0,0,0);
    accH[0][1] = __builtin_amdgcn_mfma_f32_16x16x32_bf16(a20,b21,accH[0][1],0,0,0);
    accH[1][0] = __builtin_amdgcn_mfma_f32_16x16x32_bf16(a21,b20,accH[1][0],0,0,0);
    accH[1][1] = __builtin_amdgcn_mfma_f32_16x16x32_bf16(a21,b21,accH[1][1],0,0,0);
  }
  #pragma unroll
  for (int mi = 0; mi < 2; ++mi){
    #pragma unroll
    for (int n = 0; n < 2; ++n){
      int c = gc0 + wc*32 + n*16 + l15;
      if (c >= H_) continue;
      float bzc = bz[c], bhc = bh[c];
      #pragma unroll
      for (int reg = 0; reg < 4; ++reg){
        int rl = wr*32 + mi*16 + kh*4 + reg;   // local row
        int r  = gr0 + rl;
        float z  = sigmoidf_(accZ[mi][n][reg] + bzc);
        float th = tanhf(accH[mi][n][reg] + bhc);
        float s  = SBUF[(size_t)r*H_ + c];
        float mn = (1.f - z)*s + z*th;
        int eid = s_eid[rl];
        m_[(size_t)eid*H_ + c] = mn;
        A3b[(size_t)r*KP + 450 + c] = f2b(mn);
      }
    }
  }
}

// Rgate: r=sigmoid(A3@[Wr;Ur]+br); rm[eid]=r*m_new; h=sum m[node_in[v]] -> hb (bf16)
__global__ __launch_bounds__(256) void k_rgate_mfma(
    const unsigned short* __restrict__ A3b, const unsigned short* __restrict__ WrUrT,
    const float* __restrict__ br, const int* __restrict__ step_eid,
    const int* __restrict__ step_v, const int* __restrict__ node_in, int t, int Dn,
    const float* __restrict__ m_, float* __restrict__ rm, unsigned short* __restrict__ hb)
{
  __shared__ unsigned short As[64*40], Bs[64*40];
  __shared__ int s_eid[64];
  __shared__ int s_noff[64][MAXD];
  const int tid = threadIdx.x;
  const int gr0 = blockIdx.y*64, gc0 = blockIdx.x*64;
  if (tid < 64){
    s_eid[tid] = step_eid[t*B_ + gr0 + tid];
    int v = step_v[t*B_ + gr0 + tid];
    for (int d = 0; d < Dn; ++d) s_noff[tid][d] = node_in[v*Dn + d]*H_;
  }
  f32x4 acc[2][2] = {};
  mfma_tile_core(A3b, WrUrT, KP, gr0, gc0, tid, As, Bs, acc);
  const int lane = tid & 63;
  const int w = tid >> 6, wr = w >> 1, wc = w & 1;
  const int l15 = lane & 15, kh = lane >> 4;
  #pragma unroll
  for (int mi = 0; mi < 2; ++mi){
    #pragma unroll
    for (int n = 0; n < 2; ++n){
      int c = gc0 + wc*32 + n*16 + l15;
      if (c >= H_) continue;
      float brc = br[c];
      #pragma unroll
      for (int reg = 0; reg < 4; ++reg){
        int rl = wr*32 + mi*16 + kh*4 + reg;
        int r  = gr0 + rl;
        float r_ = sigmoidf_(acc[mi][n][reg] + brc);
        int eid = s_eid[rl];
        float mn = m_[(size_t)eid*H_ + c];
        rm[(size_t)eid*H_ + c] = r_*mn;
        float h = 0.f;
        for (int d = 0; d < Dn; ++d) h += m_[s_noff[rl][d] + c];
        hb[(size_t)(t*B_ + r)*H_ + c] = f2b(h);
      }
    }
  }
}

// Head GEMM: C = act(A@B + bias); f32 store (c<Nact) and/or bf16 store (pads zeroed).
__global__ __launch_bounds__(256) void k_head_mfma(
    const unsigned short* __restrict__ A, const unsigned short* __restrict__ BT, int K,
    const float* __restrict__ bias, int Nact, int relu,
    float* __restrict__ outF, int ldF, unsigned short* __restrict__ outB, int ldB)
{
  __shared__ unsigned short As[64*40], Bs[64*40];
  const int tid = threadIdx.x;
  const int gr0 = blockIdx.y*64, gc0 = blockIdx.x*64;
  f32x4 acc[2][2] = {};
  mfma_tile_core(A, BT, K, gr0, gc0, tid, As, Bs, acc);
  const int lane = tid & 63;
  const int w = tid >> 6, wr = w >> 1, wc = w & 1;
  const int l15 = lane & 15, kh = lane >> 4;
  #pragma unroll
  for (int mi = 0; mi < 2; ++mi){
    #pragma unroll
    for (int n = 0; n < 2; ++n){
      int c = gc0 + wc*32 + n*16 + l15;
      float bc = (c < Nact) ? bias[c] : 0.f;
      #pragma unroll
      for (int reg = 0; reg < 4; ++reg){
        int r = gr0 + wr*32 + mi*16 + kh*4 + reg;
        float v = acc[mi][n][reg] + bc;
        if (relu) v = fmaxf(v, 0.f);
        if (outF && c < Nact) outF[(size_t)r*ldF + c] = v;
        if (outB && c < ldB)  outB[(size_t)r*ldB + c] = (c < Nact) ? f2b(v) : (unsigned short)0;
      }
    }
  }
}

// p-head GEMM with fused Us-dot: plog[r] += sum_c relu(acc+bu)*Us[c]
__global__ __launch_bounds__(256) void k_head_p(
    const unsigned short* __restrict__ A, const unsigned short* __restrict__ BT,
    const float* __restrict__ bu_, const float* __restrict__ Us, float* __restrict__ plog)
{
  __shared__ unsigned short As[64*40], Bs[64*40];
  const int tid = threadIdx.x;
  const int gr0 = blockIdx.y*64, gc0 = blockIdx.x*64;
  f32x4 acc[2][2] = {};
  mfma_tile_core(A, BT, 960, gr0, gc0, tid, As, Bs, acc);
  const int lane = tid & 63;
  const int w = tid >> 6, wr = w >> 1, wc = w & 1;
  const int l15 = lane & 15, kh = lane >> 4;
  #pragma unroll
  for (int mi = 0; mi < 2; ++mi){
    float rowsum[4] = {0.f,0.f,0.f,0.f};
    #pragma unroll
    for (int n = 0; n < 2; ++n){
      int c = gc0 + wc*32 + n*16 + l15;
      float uc = 0.f, bc = 0.f;
      if (c < H_){ uc = Us[c]; bc = bu_[c]; }
      #pragma unroll
      for (int reg = 0; reg < 4; ++reg){
        float v = fmaxf(acc[mi][n][reg] + bc, 0.f);
        rowsum[reg] += (c < H_) ? v*uc : 0.f;
      }
    }
    #pragma unroll
    for (int reg = 0; reg < 4; ++reg){
      float p = rowsum[reg];
      p += __shfl_xor(p,1); p += __shfl_xor(p,2);
      p += __shfl_xor(p,4); p += __shfl_xor(p,8);
      if (l15 == 0) atomicAdd(plog + gr0 + wr*32 + mi*16 + kh*4 + reg, p);
    }
  }
}

// ---------------------------------------------------------------------------
// Builders (wave-per-row, vectorized, write pads -> no big memsets needed)
__global__ __launch_bounds__(256) void k_build_Aq(const unsigned short* __restrict__ hb,
    const float* __restrict__ tv, const int* __restrict__ q_rows,
    unsigned short* __restrict__ Aq, int nq){
  int w = blockIdx.x*4 + (threadIdx.x>>6), lane = threadIdx.x & 63;
  int nw = gridDim.x*4;
  for (int i = w; i < nq; i += nw){
    int row = q_rows[i]; int b = row & (B_-1);
    unsigned short* dst = Aq + (size_t)i*512;
    if (row < B_){
      for (int j2 = lane; j2 < 225; j2 += 64) ((unsigned int*)dst)[j2] = 0u;
    } else {
      const unsigned int* src = (const unsigned int*)(hb + (size_t)(row-B_)*H_);
      for (int j2 = lane; j2 < 225; j2 += 64) ((unsigned int*)dst)[j2] = src[j2];
    }
    int k = 450 + lane;
    if (k < 512){
      unsigned short v = 0;
      if (k < 506) v = f2b(tv[b*L_ + (k-450)]);
      dst[k] = v;
    }
  }
}

__global__ __launch_bounds__(256) void k_build_Ap(const unsigned short* __restrict__ hb,
    const float* __restrict__ x, const float* __restrict__ tv,
    const int* __restrict__ root_ids, const int* __restrict__ step_v,
    unsigned short* __restrict__ Ap){
  int w = blockIdx.x*4 + (threadIdx.x>>6), lane = threadIdx.x & 63;
  int nw = gridDim.x*4;
  for (int i = w; i < NPROWS; i += nw){
    int b = i & (B_-1);
    unsigned short* dst = Ap + (size_t)i*960;
    int xn = (i < B_) ? root_ids[b] : step_v[i - B_];
    const float2* xr = (const float2*)(x + (size_t)xn*H_);
    for (int j2 = lane; j2 < 225; j2 += 64){
      float2 v = xr[j2];
      ((unsigned int*)dst)[j2] = pack2(v.x, v.y);
    }
    if (i < B_){
      for (int j2 = lane; j2 < 225; j2 += 64) ((unsigned int*)(dst + 450))[j2] = 0u;
    } else {
      const unsigned int* hr = (const unsigned int*)(hb + (size_t)(i-B_)*H_);
      for (int j2 = lane; j2 < 225; j2 += 64) ((unsigned int*)(dst + 450))[j2] = hr[j2];
    }
    int k = 900 + lane;
    if (k < 960){
      unsigned short v = 0;
      if (k < 956) v = f2b(tv[b*L_ + (k-900)]);
      dst[k] = v;
    }
  }
}

// ---------------------------------------------------------------------------
// q reduce: wave-per-row, register-cached row, shuffle reductions
__global__ __launch_bounds__(256) void k_qreduce2(const float* __restrict__ logits,
    const int* __restrict__ q_tgt, int nq, float* __restrict__ out){
  int w = blockIdx.x*4 + (threadIdx.x>>6), lane = threadIdx.x & 63;
  int nw = gridDim.x*4;
  float qloss = 0.f, qacc = 0.f;
  for (int i = w; i < nq; i += nw){
    const float4* lr4 = (const float4*)(logits + (size_t)i*V_);
    float4 vals[4]; int cnt = 0;
    float mx = -INFINITY; int mi = 0x7fffffff;
    for (int j4 = lane; j4 < 195; j4 += 64){
      float4 v = lr4[j4]; vals[cnt++] = v;
      #pragma unroll
      for (int u = 0; u < 4; ++u){
        float f = ((float*)&v)[u];
        if (f > mx){ mx = f; mi = j4*4 + u; }
      }
    }
    #pragma unroll
    for (int off = 32; off; off >>= 1){
      float omx = __shfl_xor(mx, off); int omi = __shfl_xor(mi, off);
      if (omx > mx || (omx == mx && omi < mi)){ mx = omx; mi = omi; }
    }
    float ps = 0.f; cnt = 0;
    for (int j4 = lane; j4 < 195; j4 += 64){
      float4 v = vals[cnt++];
      ps += expf(v.x-mx) + expf(v.y-mx) + expf(v.z-mx) + expf(v.w-mx);
    }
    #pragma unroll
    for (int off = 32; off; off >>= 1) ps += __shfl_xor(ps, off);
    if (lane == 0){
      int tg = q_tgt[i];
      float lt = logits[(size_t)i*V_ + tg];
      qloss += mx + logf(ps) - lt;
      qacc  += (mi == tg) ? 1.f : 0.f;
    }
  }
  if (lane == 0){
    atomicAdd(out+0, qloss*(1.0f/B_));
    atomicAdd(out+2, qacc *(1.0f/(float)nq));
  }
}

// p final: BCE + acc from plog
__global__ __launch_bounds__(256) void k_pfinal(const float* __restrict__ plog,
    const float* __restrict__ bs, const int* __restrict__ p_tgt, float* __restrict__ out){
  int i = blockIdx.x*256 + threadIdx.x;
  float loss = 0.f, acc = 0.f;
  if (i < NPROWS){
    float pl = plog[i] + bs[0];
    float tgt = (float)p_tgt[i];
    loss = fmaxf(pl, 0.f) + log1pf(expf(-fabsf(pl))) - pl*tgt;
    acc = (((pl > 0.f) ? 1 : 0) == p_tgt[i]) ? 1.f : 0.f;
  }
  #pragma unroll
  for (int off = 32; off; off >>= 1){
    loss += __shfl_xor(loss, off); acc += __shfl_xor(acc, off);
  }
  if ((threadIdx.x & 63) == 0){
    atomicAdd(out+1, loss*(1.0f/B_));
    atomicAdd(out+3, acc *(1.0f/(float)NPROWS));
  }
}

// ---------------------------------------------------------------------------
extern "C" void kernel_launch(void* const* d_in, const int* in_sizes, int n_in,
                              void* d_out, int out_size, void* d_ws, size_t ws_size,
                              hipStream_t stream){
  const float* tree_vec = (const float*)d_in[0];
  const float* emb  = (const float*)d_in[1];
  const float* Wz   = (const float*)d_in[2];
  const float* bz   = (const float*)d_in[3];
  const float* Wh   = (const float*)d_in[4];
  const float* bh   = (const float*)d_in[5];
  const float* Wr   = (const float*)d_in[6];
  const float* Ur   = (const float*)d_in[7];
  const float* br   = (const float*)d_in[8];
  const float* Ww   = (const float*)d_in[9];
  const float* bw   = (const float*)d_in[10];
  const float* Uw   = (const float*)d_in[11];
  const float* bu   = (const float*)d_in[12];
  const float* Wo   = (const float*)d_in[13];
  const float* bo   = (const float*)d_in[14];
  const float* Us   = (const float*)d_in[15];
  const float* bs   = (const float*)d_in[16];
  const int* wid      = (const int*)d_in[17];
  const int* root_ids = (const int*)d_in[18];
  const int* edge_src = (const int*)d_in[19];
  const int* edge_dst = (const int*)d_in[20];
  const int* edge_pred= (const int*)d_in[21];
  const int* node_in  = (const int*)d_in[22];
  const int* step_eid = (const int*)d_in[23];
  const int* step_v   = (const int*)d_in[24];
  const int* q_rows   = (const int*)d_in[25];
  const int* q_tgt    = (const int*)d_in[26];
  const int* p_tgt    = (const int*)d_in[27];
  int P  = in_sizes[21] / NEDGES;  if (P > MAXP) P = MAXP;
  int Dn = in_sizes[22] / NNODES;  if (Dn > MAXD) Dn = MAXD;
  int nq = in_sizes[25];           // 10240

  char* ws = (char*)d_ws;
  // --- fixed layout ---
  const size_t X_OFF   = 0;                        // f32 [10240][450]
  const size_t HB_OFF  = 18432000;                 // bf16 [T*B][450]
  const size_t M_OFF   = 35942400;                 // f32 [(E+1)][450] (pad to 35,022,848)
  const size_t RM_OFF  = M_OFF + 35022848;
  const size_t A_OFF   = RM_OFF + 35022848;        // = 105,988,096
  const size_t A1B_OFF = A_OFF;                    // bf16 [512][928]
  const size_t A2B_OFF = A1B_OFF + 950272;
  const size_t A3B_OFF = A2B_OFF + 950272;
  const size_t SB_OFF  = A3B_OFF + 950272;         // f32 [512][450]
  const size_t WZT_OFF = SB_OFF + 921600;          // bf16 [512][928]
  const size_t WHT_OFF = WZT_OFF + 950272;
  const size_t WRT_OFF = WHT_OFF + 950272;
  const size_t WWT_OFF = WRT_OFF + 950272;         // bf16 [512][512]
  const size_t UWT_OFF = WWT_OFF + 524288;         // bf16 [512][960]
  const size_t WOT_OFF = UWT_OFF + 983040;         // bf16 [832][512]
  // overlays in dead m/rm region after scan:
  const size_t AQ_OFF  = M_OFF;                    // bf16 [10240][512] = 10,485,760
  const size_t LQ_OFF  = M_OFF + 10485760;         // f32 [10240][780] = 31,948,800
  const size_t HQB_OFF = M_OFF + 42434560;         // bf16 [10240][512] = 10,485,760
  const size_t PL_OFF  = M_OFF + 52920320;         // f32 [19968] = 79,872
  const size_t AP_OFF  = M_OFF;                    // bf16 [19968][960] = 38,338,560

  float* x  = (float*)(ws + X_OFF);
  unsigned short* hb = (unsigned short*)(ws + HB_OFF);
  float* m_ = (float*)(ws + M_OFF);
  float* rm = (float*)(ws + RM_OFF);
  unsigned short* A1b = (unsigned short*)(ws + A1B_OFF);
  unsigned short* A2b = (unsigned short*)(ws + A2B_OFF);
  unsigned short* A3b = (unsigned short*)(ws + A3B_OFF);
  float* SBUF = (float*)(ws + SB_OFF);
  unsigned short* WzT = (unsigned short*)(ws + WZT_OFF);
  unsigned short* WhT = (unsigned short*)(ws + WHT_OFF);
  unsigned short* WrUrT = (unsigned short*)(ws + WRT_OFF);
  unsigned short* WwT = (unsigned short*)(ws + WWT_OFF);
  unsigned short* UwT = (unsigned short*)(ws + UWT_OFF);
  unsigned short* WoT = (unsigned short*)(ws + WOT_OFF);

  // zero init: m/rm (sentinel + unvisited-edge rows), A K-pads, out
  hipMemsetAsync(ws + M_OFF, 0, 2*35022848ull, stream);
  hipMemsetAsync(ws + A1B_OFF, 0, 3*950272ull, stream);
  hipMemsetAsync(d_out, 0, (size_t)out_size*sizeof(float), stream);

  k_gather_x<<<2560, 256, 0, stream>>>(emb, wid, x);

  k_wt<<<512, 256, 0, stream>>>(Wz, Wz, 900, 900, 450, WzT, KP);
  k_wt<<<512, 256, 0, stream>>>(Wh, Wh, 900, 900, 450, WhT, KP);
  k_wt<<<512, 256, 0, stream>>>(Wr, Ur, 450, 900, 450, WrUrT, KP);
  k_wt<<<512, 256, 0, stream>>>(Ww, Ww, 506, 506, 450, WwT, 512);
  k_wt<<<512, 256, 0, stream>>>(Uw, Uw, 956, 956, 450, UwT, 960);
  k_wt<<<832, 256, 0, stream>>>(Wo, Wo, 450, 450, 780, WoT, 512);

  // ---- 38-step scan ----
  dim3 gScan(8, 8);
  for (int t = 0; t < T_; ++t){
    k_prep2<<<dim3(B_,4), 64, 0, stream>>>(x, m_, rm, edge_src, edge_dst, edge_pred,
                                           step_eid, t, P, A1b, A2b, A3b, SBUF);
    k_gate_mfma<<<gScan, 256, 0, stream>>>(A1b, A2b, WzT, WhT, bz, bh, SBUF,
                                           step_eid, t, m_, A3b);
    k_rgate_mfma<<<gScan, 256, 0, stream>>>(A3b, WrUrT, br, step_eid, step_v,
                                            node_in, t, Dn, m_, rm, hb);
  }

  // ---- q head ----
  unsigned short* Aq  = (unsigned short*)(ws + AQ_OFF);
  float* logitsq      = (float*)(ws + LQ_OFF);
  unsigned short* hqb = (unsigned short*)(ws + HQB_OFF);
  float* plog         = (float*)(ws + PL_OFF);
  hipMemsetAsync(plog, 0, (size_t)NPROWS*4, stream);

  k_build_Aq<<<640, 256, 0, stream>>>(hb, tree_vec, q_rows, Aq, nq);
  k_head_mfma<<<dim3(8, nq/64), 256, 0, stream>>>(Aq, WwT, 512, bw, H_, 1,
      nullptr, 0, hqb, 512);
  k_head_mfma<<<dim3(13, nq/64), 256, 0, stream>>>(hqb, WoT, 512, bo, V_, 0,
      logitsq, V_, nullptr, 0);
  k_qreduce2<<<320, 256, 0, stream>>>(logitsq, q_tgt, nq, (float*)d_out);

  // ---- p head (reuses M region; q buffers dead except plog which sits above) ----
  unsigned short* Ap = (unsigned short*)(ws + AP_OFF);
  k_build_Ap<<<1248, 256, 0, stream>>>(hb, x, tree_vec, root_ids, step_v, Ap);
  k_head_p<<<dim3(8, NPROWS/64), 256, 0, stream>>>(Ap, UwT, bu, Us, plog);
  k_pfinal<<<78, 256, 0, stream>>>(plog, bs, p_tgt, (float*)d_out);
}